// Round 2
// baseline (1811.414 us; speedup 1.0000x reference)
//
#include <hip/hip_runtime.h>
#include <hip/hip_bf16.h>

// LSTM encoder, fused persistent kernel. Inputs are fp32 (reference dtypes);
// we convert weights/x/h to bf16 for MFMA, keep c-state and gate accum in fp32.
// B=64, T=2048, D=H=128, G=4H=512. 16 WGs x 512 threads; 4 batch rows/WG.
// Per step: gates = bias + x_t*Wih^T + h*Whh^T via mfma_f32_16x16x32_bf16
// (M=16 tile, rows 0-3 valid), gate compaction through LDS so every thread
// does exactly one (row,hcol) activation/c-update.

namespace {

constexpr int T_LEN = 2048;
constexpr int Bsz   = 64;
constexpr int Dd    = 128;   // embedding dim == K for Wih
constexpr int Hh    = 128;   // hidden dim  == K for Whh
constexpr int Gg    = 512;   // 4*H gate columns
constexpr int NWG   = 16;    // workgroups
constexpr int BPW   = Bsz / NWG;  // 4 batch rows per WG
constexpr int NT    = 512;   // threads per WG (8 waves)
constexpr int XS    = 136;   // LDS row stride in shorts (272 B: 2-way bank alias = free)

typedef __attribute__((ext_vector_type(8))) short   short8;   // 8 bf16 (4 VGPRs)
typedef __attribute__((ext_vector_type(4))) float   floatx4;  // MFMA acc
typedef __attribute__((ext_vector_type(2))) unsigned int uintx2;

#define MFMA16(a, b, c) __builtin_amdgcn_mfma_f32_16x16x32_bf16((a), (b), (c), 0, 0, 0)

__device__ __forceinline__ float sigmoidf_(float x) {
    // 1/(1+e^-x); e^-x -> 2^(-x*log2e). Graceful at extremes (rcp(inf)=0).
    return __builtin_amdgcn_rcpf(1.0f + __builtin_amdgcn_exp2f(x * -1.44269504f));
}
__device__ __forceinline__ float tanhf_(float x) {
    // 1 - 2/(1+e^{2x})
    return __builtin_fmaf(-2.0f,
        __builtin_amdgcn_rcpf(1.0f + __builtin_amdgcn_exp2f(x * 2.88539008f)), 1.0f);
}
__device__ __forceinline__ unsigned short f2bf(float f) {
    __hip_bfloat16 h = __float2bfloat16(f);  // RNE
    union { __hip_bfloat16 b; unsigned short u; } v; v.b = h; return v.u;
}
__device__ __forceinline__ uintx2 f4bf(const float4 v) {
    union { unsigned short us[4]; uintx2 u2; } p;
    p.us[0] = f2bf(v.x); p.us[1] = f2bf(v.y); p.us[2] = f2bf(v.z); p.us[3] = f2bf(v.w);
    return p.u2;
}
__device__ __forceinline__ short8 ld8bf(const float* p) {
    const float4 a = *reinterpret_cast<const float4*>(p);
    const float4 b = *reinterpret_cast<const float4*>(p + 4);
    short8 s;
    s[0] = (short)f2bf(a.x); s[1] = (short)f2bf(a.y);
    s[2] = (short)f2bf(a.z); s[3] = (short)f2bf(a.w);
    s[4] = (short)f2bf(b.x); s[5] = (short)f2bf(b.y);
    s[6] = (short)f2bf(b.z); s[7] = (short)f2bf(b.w);
    return s;
}

__global__ __launch_bounds__(NT, 2) void lstm_fused(
    const int*   __restrict__ tokens,   // [64][2048] int32
    const float* __restrict__ emb,      // [50257][128] fp32
    const float* __restrict__ Wih,      // [512][128] fp32
    const float* __restrict__ Whh,      // [512][128] fp32
    const float* __restrict__ bih,      // [512] fp32
    const float* __restrict__ bhh,      // [512] fp32
    float*       __restrict__ out)      // [2][64][128] fp32 (h then c)
{
    __shared__ unsigned short xbuf[2][16 * XS];  // x_t tile bf16, A-layout rows (rows 4-15 stay 0)
    __shared__ unsigned short hbuf[2][16 * XS];  // h tile bf16 (rows 4-15 stay 0)
    __shared__ float scratch[4 * Gg];            // gates fp32, [row r][gate n]

    const int tid  = threadIdx.x;
    const int w    = tid >> 6;        // wave 0..7  -> owns gate-cols [w*16, w*16+16) per block q
    const int l    = tid & 63;
    const int quad = l >> 4;
    const int cl   = l & 15;
    const int bbase = blockIdx.x * BPW;

    // activation-phase mapping: one (row, hcol) per thread
    const int rr = tid >> 7;          // 0..3 (batch row within WG)
    const int hh = tid & 127;         // 0..127 (hidden col)

    // ---- preload weight B-fragments (fp32 -> bf16 once): B[k][n] = W[n][k] ----
    short8 wih[4][4], whh[4][4];      // [gate quadrant q][k-chunk kk]
    float  bias[4];
#pragma unroll
    for (int q = 0; q < 4; ++q) {
        const int n = q * 128 + w * 16 + cl;
#pragma unroll
        for (int kk = 0; kk < 4; ++kk) {
            const int k0 = kk * 32 + quad * 8;
            wih[q][kk] = ld8bf(Wih + n * Dd + k0);
            whh[q][kk] = ld8bf(Whh + n * Hh + k0);
        }
        bias[q] = bih[n] + bhh[n];
    }

    // ---- zero LDS tiles (rows 4-15 must stay zero forever) ----
    for (int i = tid; i < 16 * XS; i += NT) {
        xbuf[0][i] = 0; xbuf[1][i] = 0; hbuf[0][i] = 0; hbuf[1][i] = 0;
    }

    // ---- embedding gather lanes: threads 0..127 stage 4 rows x 128 cols ----
    // lane loads float4 (4 cols), converts to 4 bf16 (8 B) at LDS store time
    const bool gact = (tid < 128);
    const int  gr = tid >> 5;         // 0..3 row
    const int  gp = tid & 31;         // 0..31 -> 4-col chunk
    float4 gdataf = {0.f, 0.f, 0.f, 0.f};
    if (gact) {
        const int tok = tokens[(bbase + gr) * T_LEN + 0];
        gdataf = *reinterpret_cast<const float4*>(emb + (size_t)tok * Dd + gp * 4);
    }
    __syncthreads();                  // zeros visible
    if (gact) {
        *reinterpret_cast<uintx2*>(&xbuf[0][gr * XS + gp * 4]) = f4bf(gdataf);
    }
    if (gact) {                       // prefetch t=1 into regs
        const int tok = tokens[(bbase + gr) * T_LEN + 1];
        gdataf = *reinterpret_cast<const float4*>(emb + (size_t)tok * Dd + gp * 4);
    }
    __syncthreads();                  // xbuf[0] ready

    // A-fragment LDS element offset: row m = cl, k = kk*32 + quad*8 (+j)
    const int afrag_el = cl * XS + quad * 8;   // + kk*32 elements

    // ---- prologue: acc = bias + x(0)*Wih^T ----
    floatx4 acc[4];
#pragma unroll
    for (int q = 0; q < 4; ++q) acc[q] = (floatx4){bias[q], bias[q], bias[q], bias[q]};
    {
        short8 xf[4];
#pragma unroll
        for (int kk = 0; kk < 4; ++kk)
            xf[kk] = *reinterpret_cast<const short8*>(&xbuf[0][afrag_el + kk * 32]);
#pragma unroll
        for (int kk = 0; kk < 4; ++kk)
#pragma unroll
            for (int q = 0; q < 4; ++q)
                acc[q] = MFMA16(xf[kk], wih[q][kk], acc[q]);
    }

    float c_state = 0.0f;
    float h_last  = 0.0f;

    for (int t = 0; t < T_LEN; ++t) {
        const int cur = t & 1, nxt = cur ^ 1;

        // h A-fragments for this step (hbuf[cur] complete since last barrier)
        short8 hf[4];
#pragma unroll
        for (int kk = 0; kk < 4; ++kk)
            hf[kk] = *reinterpret_cast<const short8*>(&hbuf[cur][afrag_el + kk * 32]);

        // stage x(t+1) (regs -> LDS), then prefetch x(t+2) (global -> regs)
        if (gact && (t + 1 < T_LEN))
            *reinterpret_cast<uintx2*>(&xbuf[nxt][gr * XS + gp * 4]) = f4bf(gdataf);
        if (gact && (t + 2 < T_LEN)) {
            const int tok = tokens[(bbase + gr) * T_LEN + (t + 2)];
            gdataf = *reinterpret_cast<const float4*>(emb + (size_t)tok * Dd + gp * 4);
        }

        // gates += h * Whh^T
#pragma unroll
        for (int kk = 0; kk < 4; ++kk)
#pragma unroll
            for (int q = 0; q < 4; ++q)
                acc[q] = MFMA16(hf[kk], whh[q][kk], acc[q]);

        // compact valid gate rows (m = quad*4+r < 4  =>  quad==0) to scratch[r][n]
        if (quad == 0) {
#pragma unroll
            for (int q = 0; q < 4; ++q) {
                const int n = q * 128 + w * 16 + cl;
#pragma unroll
                for (int r = 0; r < 4; ++r)
                    scratch[r * Gg + n] = acc[q][r];
            }
        }
        __syncthreads();  // barrier 1: gates ready, xbuf[nxt] ready

        // overlapped: acc = bias + x(t+1)*Wih^T  (independent of activations)
#pragma unroll
        for (int q = 0; q < 4; ++q) acc[q] = (floatx4){bias[q], bias[q], bias[q], bias[q]};
        if (t + 1 < T_LEN) {
            short8 xf[4];
#pragma unroll
            for (int kk = 0; kk < 4; ++kk)
                xf[kk] = *reinterpret_cast<const short8*>(&xbuf[nxt][afrag_el + kk * 32]);
#pragma unroll
            for (int kk = 0; kk < 4; ++kk)
#pragma unroll
                for (int q = 0; q < 4; ++q)
                    acc[q] = MFMA16(xf[kk], wih[q][kk], acc[q]);
        }

        // activations: one (rr,hh) per thread; gate order i,f,g,o
        {
            const float iv = scratch[rr * Gg + hh];
            const float fv = scratch[rr * Gg + 128 + hh];
            const float gv = scratch[rr * Gg + 256 + hh];
            const float ov = scratch[rr * Gg + 384 + hh];
            const float si = sigmoidf_(iv);
            const float sf = sigmoidf_(fv);
            const float so = sigmoidf_(ov);
            const float tg = tanhf_(gv);
            c_state = sf * c_state + si * tg;
            h_last  = so * tanhf_(c_state);
            hbuf[nxt][rr * XS + hh] = f2bf(h_last);
        }
        __syncthreads();  // barrier 2: h(t+1) ready; scratch safe to overwrite
    }

    // epilogue: out = concat(h[1,64,128], c[1,64,128]) as fp32
    const int ob = (bbase + rr) * Hh + hh;
    out[ob]            = h_last;
    out[Bsz * Hh + ob] = c_state;
}

}  // namespace

extern "C" void kernel_launch(void* const* d_in, const int* in_sizes, int n_in,
                              void* d_out, int out_size, void* d_ws, size_t ws_size,
                              hipStream_t stream) {
    (void)in_sizes; (void)n_in; (void)out_size; (void)d_ws; (void)ws_size;
    const int*   tokens = (const int*)d_in[0];
    const float* emb    = (const float*)d_in[1];
    const float* Wih    = (const float*)d_in[2];
    const float* Whh    = (const float*)d_in[3];
    const float* bih    = (const float*)d_in[4];
    const float* bhh    = (const float*)d_in[5];
    lstm_fused<<<NWG, NT, 0, stream>>>(tokens, emb, Wih, Whh, bih, bhh,
                                       (float*)d_out);
}